// Round 3
// baseline (204.355 us; speedup 1.0000x reference)
//
#include <hip/hip_runtime.h>
#include <math.h>

#define KD 64
#define VD 64
#define RPB 256          // rows per block
#define RPL 16           // rows per lane-group pass (RPB/16)

typedef float vfloat4 __attribute__((ext_vector_type(4)));

__device__ __forceinline__ vfloat4 ntload4(const float* p) {
    return __builtin_nontemporal_load(reinterpret_cast<const vfloat4*>(p));
}
__device__ __forceinline__ void ntstore4(float* p, vfloat4 v) {
    __builtin_nontemporal_store(v, reinterpret_cast<vfloat4*>(p));
}

// ---------------------------------------------------------------------------
// Fused kernel: one block = (batch b, 256-row slice). Streams value_memory
// AND key_memory rows interleaved:
//   sim = (n<=it) ? dot(vm[n], new_value) : 0    (xor-butterfly -> all lanes)
//   p = exp(sim) kept in registers (no global round-trip)
//   new_value_memory / new_key_memory copies fused with the reads
//   partials: Spart, PCpart (scalar), pread[64] (weighted key sum)
// ---------------------------------------------------------------------------
__global__ __launch_bounds__(256) void fused_stream(
    const float* __restrict__ value_memory,
    const float* __restrict__ key_memory,
    const float* __restrict__ new_value,
    const float* __restrict__ new_key,
    const int*   __restrict__ iteration,
    const float* __restrict__ conf_w,
    const float* __restrict__ conf_b,
    float* __restrict__ new_value_memory,
    float* __restrict__ new_key_memory,
    float* __restrict__ Spart,
    float* __restrict__ PCpart,
    float* __restrict__ pread,
    int M, int max_it)
{
    const int blocks_per_batch = M / RPB;
    const int b     = blockIdx.x / blocks_per_batch;
    const int split = blockIdx.x % blocks_per_batch;
    const int row0  = split * RPB;
    const int it    = iteration[b];
    const float cw  = conf_w[0], cb = conf_b[0];

    const int tid = threadIdx.x;
    const int l   = tid & 63;
    const int w   = tid >> 6;
    const int c4  = (l & 15) * 4;
    const int rsub = w * 4 + (l >> 4);   // 0..15

    const vfloat4 nv = *reinterpret_cast<const vfloat4*>(new_value + (size_t)b * VD + c4);
    const vfloat4 nk = *reinterpret_cast<const vfloat4*>(new_key   + (size_t)b * KD + c4);
    const float* vmb  = value_memory     + (size_t)b * M * VD;
    const float* kmb  = key_memory       + (size_t)b * M * KD;
    float*       ovmb = new_value_memory + (size_t)b * M * VD;
    float*       okmb = new_key_memory   + (size_t)b * M * KD;

    float sloc = 0.f, pcloc = 0.f;
    vfloat4 acc = (vfloat4){0.f, 0.f, 0.f, 0.f};

    #pragma unroll
    for (int i = 0; i < RPL; ++i) {
        const int n = row0 + rsub + i * 16;
        const size_t off = (size_t)n * 64 + c4;

        vfloat4 v = ntload4(vmb + off);
        vfloat4 k = ntload4(kmb + off);

        float part = fmaf(v.x, nv.x, fmaf(v.y, nv.y, fmaf(v.z, nv.z, v.w * nv.w)));
        part += __shfl_xor(part, 1);
        part += __shfl_xor(part, 2);
        part += __shfl_xor(part, 4);
        part += __shfl_xor(part, 8);           // all 16 lanes hold the dot

        const float s = (n <= it) ? part : 0.0f;
        const float p = expf(s);
        sloc  += p;
        pcloc += p * (1.0f / (1.0f + expf(-(s * cw + cb))));

        acc.x = fmaf(p, k.x, acc.x); acc.y = fmaf(p, k.y, acc.y);
        acc.z = fmaf(p, k.z, acc.z); acc.w = fmaf(p, k.w, acc.w);

        vfloat4 ovv, ovk;
        if (n == it)          { ovv = nv; ovk = nk; }
        else if (n == max_it) { ovv = (vfloat4){0,0,0,0}; ovk = (vfloat4){0,0,0,0}; }
        else                  { ovv = v;  ovk = k; }
        ntstore4(ovmb + off, ovv);
        ntstore4(okmb + off, ovk);
    }

    // ---- scalar partials: sloc identical across a 16-lane group; xor 16/32
    //      sums the 4 groups of the wave (each counted once). ----
    sloc  += __shfl_xor(sloc, 16);  sloc  += __shfl_xor(sloc, 32);
    pcloc += __shfl_xor(pcloc, 16); pcloc += __shfl_xor(pcloc, 32);

    // ---- column partials: lanes sharing (l&15) hold same columns ----
    acc.x += __shfl_xor(acc.x, 16); acc.y += __shfl_xor(acc.y, 16);
    acc.z += __shfl_xor(acc.z, 16); acc.w += __shfl_xor(acc.w, 16);
    acc.x += __shfl_xor(acc.x, 32); acc.y += __shfl_xor(acc.y, 32);
    acc.z += __shfl_xor(acc.z, 32); acc.w += __shfl_xor(acc.w, 32);

    __shared__ float sS[4], sPC[4];
    __shared__ float racc[4][64];
    if (l == 0) { sS[w] = sloc; sPC[w] = pcloc; }
    if (l < 16) {
        racc[w][c4 + 0] = acc.x; racc[w][c4 + 1] = acc.y;
        racc[w][c4 + 2] = acc.z; racc[w][c4 + 3] = acc.w;
    }
    __syncthreads();
    if (tid == 0) {
        Spart [b * blocks_per_batch + split] = sS[0] + sS[1] + sS[2] + sS[3];
        PCpart[b * blocks_per_batch + split] = sPC[0] + sPC[1] + sPC[2] + sPC[3];
    }
    if (tid < 64) {
        const float sumk = racc[0][tid] + racc[1][tid] + racc[2][tid] + racc[3][tid];
        pread[((size_t)b * blocks_per_batch + split) * 64 + tid] = sumk;
    }
}

// ---------------------------------------------------------------------------
// K3: read[b,k] = sigmoid(gate[b,k]) * (sum_s pread[b,s,k]) / S   (k<64)
//     read[b,64] = sigmoid(gate[b,64]) * PC / S ; zero if it<=1
// ---------------------------------------------------------------------------
__global__ __launch_bounds__(256) void k3_finalize(
    const float* __restrict__ pread,
    const float* __restrict__ Spart,
    const float* __restrict__ PCpart,
    const float* __restrict__ gate,
    const int*   __restrict__ iteration,
    float* __restrict__ out_read,
    int B, int splits)
{
    const int idx = blockIdx.x * 256 + threadIdx.x;
    if (idx >= B * (KD + 1)) return;
    const int b = idx / (KD + 1);
    const int k = idx % (KD + 1);

    float S = 0.f;
    for (int s = 0; s < splits; ++s) S += Spart[b * splits + s];

    float r = 0.f;
    if (k < KD) {
        for (int s = 0; s < splits; ++s)
            r += pread[((size_t)b * splits + s) * 64 + k];
    } else {
        for (int s = 0; s < splits; ++s) r += PCpart[b * splits + s];
    }
    const float g = gate[(size_t)b * (KD + 1) + k];
    float val = (1.0f / (1.0f + expf(-g))) * (r / S);
    if (iteration[b] <= 1) val = 0.0f;
    out_read[idx] = val;
}

extern "C" void kernel_launch(void* const* d_in, const int* in_sizes, int n_in,
                              void* d_out, int out_size, void* d_ws, size_t ws_size,
                              hipStream_t stream) {
    const float* new_key      = (const float*)d_in[0];
    const float* new_value    = (const float*)d_in[1];
    const float* key_memory   = (const float*)d_in[2];
    const float* value_memory = (const float*)d_in[3];
    const float* gate         = (const float*)d_in[4];
    const float* conf_w       = (const float*)d_in[5];
    const float* conf_b       = (const float*)d_in[6];
    const int*   iteration    = (const int*)d_in[7];

    const int B = in_sizes[0] / KD;              // 512
    const int M = in_sizes[2] / in_sizes[0];     // 2048
    const int max_it = M - 1;
    const int splits = M / RPB;                  // 8

    float* out_km   = (float*)d_out;
    float* out_vm   = out_km + (size_t)B * M * KD;
    float* out_read = out_vm + (size_t)B * M * VD;

    float* Spart  = (float*)d_ws;                        // B*splits
    float* PCpart = Spart + (size_t)B * splits;          // B*splits
    float* pread  = PCpart + (size_t)B * splits;         // B*splits*64

    fused_stream<<<B * splits, 256, 0, stream>>>(
        value_memory, key_memory, new_value, new_key, iteration,
        conf_w, conf_b, out_vm, out_km, Spart, PCpart, pread, M, max_it);

    const int total = B * (KD + 1);
    k3_finalize<<<(total + 255) / 256, 256, 0, stream>>>(
        pread, Spart, PCpart, gate, iteration, out_read, B, splits);
}

// Round 4
// 192.879 us; speedup vs baseline: 1.0595x; 1.0595x over previous
//
#include <hip/hip_runtime.h>
#include <math.h>

#define KD 64
#define VD 64
#define MM 2048          // rows (fixed by problem)
#define NITER (MM / 64)  // rows per lane-group = 32

typedef float vfloat4 __attribute__((ext_vector_type(4)));

__device__ __forceinline__ vfloat4 ntload4(const float* p) {
    return __builtin_nontemporal_load(reinterpret_cast<const vfloat4*>(p));
}
__device__ __forceinline__ void ntstore4(float* p, vfloat4 v) {
    __builtin_nontemporal_store(v, reinterpret_cast<vfloat4*>(p));
}
__device__ __forceinline__ float fastsig(float x) {
    return __builtin_amdgcn_rcpf(1.0f + __expf(-x));
}

// ---------------------------------------------------------------------------
// One block per batch (1024 threads = 16 waves, 64 lane-groups of 16 lanes).
// Lane-group g owns rows n === g (mod 64); 32 rows each.
// Phase 1: stream value_memory (1R+1W): sim -> p (to LDS), copy rows.
// Phase 2: stream key_memory  (1R+1W): acc += p*key, copy rows.
// Special rows (it, max_it) skipped in-loop, patched by owner lanes after.
// Epilogue: in-block reduction -> final gated read vector (no 2nd kernel).
// ---------------------------------------------------------------------------
__global__ __launch_bounds__(1024) void fused_all(
    const float* __restrict__ value_memory,
    const float* __restrict__ key_memory,
    const float* __restrict__ new_value,
    const float* __restrict__ new_key,
    const int*   __restrict__ iteration,
    const float* __restrict__ conf_w,
    const float* __restrict__ conf_b,
    const float* __restrict__ gate,
    float* __restrict__ new_value_memory,
    float* __restrict__ new_key_memory,
    float* __restrict__ out_read,
    int max_it)
{
    const int b   = blockIdx.x;
    const int tid = threadIdx.x;
    const int l   = tid & 63;
    const int w   = tid >> 6;            // wave 0..15
    const int c4  = (l & 15) * 4;        // column offset
    const int g   = w * 4 + (l >> 4);    // lane-group 0..63 (row mod 64)

    const int it   = iteration[b];
    const float cw = conf_w[0], cb = conf_b[0];

    __shared__ float pS[MM];             // 8 KB
    __shared__ float sS[16], sPC[16];
    __shared__ float racc[16][64];       // 4 KB

    const vfloat4 nv = *reinterpret_cast<const vfloat4*>(new_value + (size_t)b * VD + c4);
    const vfloat4 nk = *reinterpret_cast<const vfloat4*>(new_key   + (size_t)b * KD + c4);
    const vfloat4 z4 = (vfloat4){0.f, 0.f, 0.f, 0.f};

    const size_t base = (size_t)g * 64 + c4;
    const float* vmb  = value_memory     + (size_t)b * MM * VD;
    const float* kmb  = key_memory       + (size_t)b * MM * KD;
    float*       ovmb = new_value_memory + (size_t)b * MM * VD;
    float*       okmb = new_key_memory   + (size_t)b * MM * KD;

    // ---------------- Phase 1: value stream ----------------
    float sloc = 0.f, pcloc = 0.f;
    #pragma unroll 8
    for (int i = 0; i < NITER; ++i) {
        const int n = i * 64 + g;
        const size_t off = base + (size_t)i * 64 * 64;
        vfloat4 v = ntload4(vmb + off);

        float part = fmaf(v.x, nv.x, fmaf(v.y, nv.y, fmaf(v.z, nv.z, v.w * nv.w)));
        part += __shfl_xor(part, 1);
        part += __shfl_xor(part, 2);
        part += __shfl_xor(part, 4);
        part += __shfl_xor(part, 8);      // all 16 lanes of group hold dot

        const float s = (n <= it) ? part : 0.0f;
        const float p = __expf(s);
        if ((l & 15) == 0) pS[n] = p;
        sloc  += p;
        pcloc += p * fastsig(fmaf(s, cw, cb));

        if (n != it && n != max_it) ntstore4(ovmb + off, v);
    }
    // patch special rows (owner lane-groups only; distinct addresses)
    if (g == 63 && it != max_it) ntstore4(ovmb + (size_t)max_it * 64 + c4, z4);
    if (g == (it & 63))          ntstore4(ovmb + (size_t)it * 64 + c4, nv);

    // ---------------- Phase 2: key stream ----------------
    vfloat4 acc = z4;
    #pragma unroll 8
    for (int i = 0; i < NITER; ++i) {
        const int n = i * 64 + g;
        const size_t off = base + (size_t)i * 64 * 64;
        vfloat4 k = ntload4(kmb + off);
        const float p = pS[n];            // same-wave LDS producer; broadcast read
        acc.x = fmaf(p, k.x, acc.x); acc.y = fmaf(p, k.y, acc.y);
        acc.z = fmaf(p, k.z, acc.z); acc.w = fmaf(p, k.w, acc.w);
        if (n != it && n != max_it) ntstore4(okmb + off, k);
    }
    if (g == 63 && it != max_it) ntstore4(okmb + (size_t)max_it * 64 + c4, z4);
    if (g == (it & 63))          ntstore4(okmb + (size_t)it * 64 + c4, nk);

    // ---------------- reductions ----------------
    // scalar partials: identical within 16-lane group; xor16/32 sums the
    // wave's 4 groups exactly once.
    sloc  += __shfl_xor(sloc, 16);  sloc  += __shfl_xor(sloc, 32);
    pcloc += __shfl_xor(pcloc, 16); pcloc += __shfl_xor(pcloc, 32);
    // column partials: lanes sharing (l&15) hold the same columns.
    acc.x += __shfl_xor(acc.x, 16); acc.y += __shfl_xor(acc.y, 16);
    acc.z += __shfl_xor(acc.z, 16); acc.w += __shfl_xor(acc.w, 16);
    acc.x += __shfl_xor(acc.x, 32); acc.y += __shfl_xor(acc.y, 32);
    acc.z += __shfl_xor(acc.z, 32); acc.w += __shfl_xor(acc.w, 32);

    if (l == 0) { sS[w] = sloc; sPC[w] = pcloc; }
    if (l < 16) {
        racc[w][c4 + 0] = acc.x; racc[w][c4 + 1] = acc.y;
        racc[w][c4 + 2] = acc.z; racc[w][c4 + 3] = acc.w;
    }
    __syncthreads();

    // ---------------- epilogue: final read vector ----------------
    if (tid < KD + 1) {
        float S = 0.f;
        #pragma unroll
        for (int ww = 0; ww < 16; ++ww) S += sS[ww];
        float r = 0.f;
        if (tid < KD) {
            #pragma unroll
            for (int ww = 0; ww < 16; ++ww) r += racc[ww][tid];
        } else {
            #pragma unroll
            for (int ww = 0; ww < 16; ++ww) r += sPC[ww];
        }
        const float gt = gate[(size_t)b * (KD + 1) + tid];
        float val = fastsig(gt) * (r / S);
        if (it <= 1) val = 0.0f;
        out_read[(size_t)b * (KD + 1) + tid] = val;
    }
}

extern "C" void kernel_launch(void* const* d_in, const int* in_sizes, int n_in,
                              void* d_out, int out_size, void* d_ws, size_t ws_size,
                              hipStream_t stream) {
    const float* new_key      = (const float*)d_in[0];
    const float* new_value    = (const float*)d_in[1];
    const float* key_memory   = (const float*)d_in[2];
    const float* value_memory = (const float*)d_in[3];
    const float* gate         = (const float*)d_in[4];
    const float* conf_w       = (const float*)d_in[5];
    const float* conf_b       = (const float*)d_in[6];
    const int*   iteration    = (const int*)d_in[7];

    const int B = in_sizes[0] / KD;              // 512
    const int M = in_sizes[2] / in_sizes[0];     // 2048 (== MM)
    const int max_it = M - 1;

    float* out_km   = (float*)d_out;
    float* out_vm   = out_km + (size_t)B * M * KD;
    float* out_read = out_vm + (size_t)B * M * VD;

    fused_all<<<B, 1024, 0, stream>>>(
        value_memory, key_memory, new_value, new_key, iteration,
        conf_w, conf_b, gate, out_vm, out_km, out_read, max_it);
}

// Round 5
// 192.064 us; speedup vs baseline: 1.0640x; 1.0042x over previous
//
#include <hip/hip_runtime.h>
#include <math.h>

#define KD 64
#define VD 64
#define MM 2048          // rows (fixed by problem)
#define NITER (MM / 64)  // rows per lane-group = 32

typedef float vfloat4 __attribute__((ext_vector_type(4)));

__device__ __forceinline__ vfloat4 ntload4(const float* p) {
    return __builtin_nontemporal_load(reinterpret_cast<const vfloat4*>(p));
}
__device__ __forceinline__ void ntstore4(float* p, vfloat4 v) {
    __builtin_nontemporal_store(v, reinterpret_cast<vfloat4*>(p));
}
__device__ __forceinline__ float fastsig(float x) {
    return __builtin_amdgcn_rcpf(1.0f + __expf(-x));
}

// ---------------------------------------------------------------------------
// One block per batch (1024 threads = 16 waves, 64 lane-groups of 16 lanes).
// Lane-group g owns rows n === g (mod 64); 32 rows each.
// Phase 1: stream value_memory (1R+1W): sim -> p (LDS), branchless copy.
// Phase 2: stream key_memory  (1R+1W): acc += p*key, branchless copy.
// Epilogue: in-block reduction -> final gated read vector. Single dispatch.
// ---------------------------------------------------------------------------
__global__ __launch_bounds__(1024) void fused_all(
    const float* __restrict__ value_memory,
    const float* __restrict__ key_memory,
    const float* __restrict__ new_value,
    const float* __restrict__ new_key,
    const int*   __restrict__ iteration,
    const float* __restrict__ conf_w,
    const float* __restrict__ conf_b,
    const float* __restrict__ gate,
    float* __restrict__ new_value_memory,
    float* __restrict__ new_key_memory,
    float* __restrict__ out_read,
    int max_it)
{
    const int b   = blockIdx.x;
    const int tid = threadIdx.x;
    const int l   = tid & 63;
    const int w   = tid >> 6;            // wave 0..15
    const int c4  = (l & 15) * 4;        // column offset
    const int g   = w * 4 + (l >> 4);    // lane-group 0..63 (row mod 64)

    const int it   = iteration[b];
    const float cw = conf_w[0], cb = conf_b[0];

    __shared__ float pS[MM];             // 8 KB
    __shared__ float sS[16], sPC[16];
    __shared__ float racc[16][64];       // 4 KB

    const vfloat4 nv = *reinterpret_cast<const vfloat4*>(new_value + (size_t)b * VD + c4);
    const vfloat4 nk = *reinterpret_cast<const vfloat4*>(new_key   + (size_t)b * KD + c4);
    const vfloat4 z4 = (vfloat4){0.f, 0.f, 0.f, 0.f};

    const size_t base = (size_t)g * 64 + c4;
    const float* vmb  = value_memory     + (size_t)b * MM * VD;
    const float* kmb  = key_memory       + (size_t)b * MM * KD;
    float*       ovmb = new_value_memory + (size_t)b * MM * VD;
    float*       okmb = new_key_memory   + (size_t)b * MM * KD;

    // ---------------- Phase 1: value stream ----------------
    float sloc = 0.f, pcloc = 0.f;
    #pragma unroll 8
    for (int i = 0; i < NITER; ++i) {
        const int n = i * 64 + g;
        const size_t off = base + (size_t)i * 64 * 64;
        vfloat4 v = ntload4(vmb + off);

        float part = fmaf(v.x, nv.x, fmaf(v.y, nv.y, fmaf(v.z, nv.z, v.w * nv.w)));
        part += __shfl_xor(part, 1);
        part += __shfl_xor(part, 2);
        part += __shfl_xor(part, 4);
        part += __shfl_xor(part, 8);      // all 16 lanes of group hold dot

        const float s = (n <= it) ? part : 0.0f;
        const float p = __expf(s);
        if ((l & 15) == 0) pS[n] = p;
        sloc  += p;
        pcloc += p * fastsig(fmaf(s, cw, cb));

        // branchless: row it -> new_value, row max_it -> 0, else copy
        vfloat4 ov = (n == max_it) ? z4 : v;
        ov = (n == it) ? nv : ov;
        ntstore4(ovmb + off, ov);
    }

    // ---------------- Phase 2: key stream ----------------
    vfloat4 acc = z4;
    #pragma unroll 16
    for (int i = 0; i < NITER; ++i) {
        const int n = i * 64 + g;
        const size_t off = base + (size_t)i * 64 * 64;
        vfloat4 k = ntload4(kmb + off);
        const float p = pS[n];            // same-wave LDS producer; broadcast read
        acc.x = fmaf(p, k.x, acc.x); acc.y = fmaf(p, k.y, acc.y);
        acc.z = fmaf(p, k.z, acc.z); acc.w = fmaf(p, k.w, acc.w);

        vfloat4 ov = (n == max_it) ? z4 : k;
        ov = (n == it) ? nk : ov;
        ntstore4(okmb + off, ov);
    }

    // ---------------- reductions ----------------
    // scalar partials: identical within 16-lane group; xor16/32 sums the
    // wave's 4 groups exactly once.
    sloc  += __shfl_xor(sloc, 16);  sloc  += __shfl_xor(sloc, 32);
    pcloc += __shfl_xor(pcloc, 16); pcloc += __shfl_xor(pcloc, 32);
    // column partials: lanes sharing (l&15) hold the same columns.
    acc.x += __shfl_xor(acc.x, 16); acc.y += __shfl_xor(acc.y, 16);
    acc.z += __shfl_xor(acc.z, 16); acc.w += __shfl_xor(acc.w, 16);
    acc.x += __shfl_xor(acc.x, 32); acc.y += __shfl_xor(acc.y, 32);
    acc.z += __shfl_xor(acc.z, 32); acc.w += __shfl_xor(acc.w, 32);

    if (l == 0) { sS[w] = sloc; sPC[w] = pcloc; }
    if (l < 16) {
        racc[w][c4 + 0] = acc.x; racc[w][c4 + 1] = acc.y;
        racc[w][c4 + 2] = acc.z; racc[w][c4 + 3] = acc.w;
    }
    __syncthreads();

    // ---------------- epilogue: final read vector ----------------
    if (tid < KD + 1) {
        float S = 0.f;
        #pragma unroll
        for (int ww = 0; ww < 16; ++ww) S += sS[ww];
        float r = 0.f;
        if (tid < KD) {
            #pragma unroll
            for (int ww = 0; ww < 16; ++ww) r += racc[ww][tid];
        } else {
            #pragma unroll
            for (int ww = 0; ww < 16; ++ww) r += sPC[ww];
        }
        const float gt = gate[(size_t)b * (KD + 1) + tid];
        float val = fastsig(gt) * (r / S);
        if (it <= 1) val = 0.0f;
        out_read[(size_t)b * (KD + 1) + tid] = val;
    }
}

extern "C" void kernel_launch(void* const* d_in, const int* in_sizes, int n_in,
                              void* d_out, int out_size, void* d_ws, size_t ws_size,
                              hipStream_t stream) {
    const float* new_key      = (const float*)d_in[0];
    const float* new_value    = (const float*)d_in[1];
    const float* key_memory   = (const float*)d_in[2];
    const float* value_memory = (const float*)d_in[3];
    const float* gate         = (const float*)d_in[4];
    const float* conf_w       = (const float*)d_in[5];
    const float* conf_b       = (const float*)d_in[6];
    const int*   iteration    = (const int*)d_in[7];

    const int B = in_sizes[0] / KD;              // 512
    const int M = in_sizes[2] / in_sizes[0];     // 2048 (== MM)
    const int max_it = M - 1;

    float* out_km   = (float*)d_out;
    float* out_vm   = out_km + (size_t)B * M * KD;
    float* out_read = out_vm + (size_t)B * M * VD;

    fused_all<<<B, 1024, 0, stream>>>(
        value_memory, key_memory, new_value, new_key, iteration,
        conf_w, conf_b, gate, out_vm, out_km, out_read, max_it);
}